// Round 5
// baseline (627.564 us; speedup 1.0000x reference)
//
#include <hip/hip_runtime.h>
#include <hip/hip_bf16.h>

// MEASUREMENT PROBE ROUND.
// The real kernel (single SiLU pass) runs < 163us and is invisible in the
// rocprof top-5, which is saturated by the harness's 1-GiB 0xAA fills
// (163-167us each). This probe makes ONE dispatch do 3 independent streaming
// SiLU passes (real in->out, plus two dummy passes over distinct 256 MiB
// d_ws regions) so the dispatch's dur exceeds the fills and its
// FETCH/WRITE/hbm_gbps counters surface. Structure per-pass is identical to
// the committed single-pass kernel (f32x4, exact-fit grid, NT stores).

typedef float f32x4 __attribute__((ext_vector_type(4)));

__device__ __forceinline__ float silu_fast(float x) {
    const float LOG2E = 1.4426950408889634f;
    float t = __builtin_amdgcn_exp2f(-x * LOG2E);
    return x * __builtin_amdgcn_rcpf(1.0f + t);
}

__device__ __forceinline__ f32x4 silu4(f32x4 v) {
    f32x4 r;
    r.x = silu_fast(v.x);
    r.y = silu_fast(v.y);
    r.z = silu_fast(v.z);
    r.w = silu_fast(v.w);
    return r;
}

__device__ __forceinline__ void silu_pass(const f32x4* __restrict__ in,
                                          f32x4* __restrict__ out,
                                          long long base) {
    f32x4 a = in[base];
    f32x4 b = in[base + 256];
    f32x4 ra = silu4(a);
    f32x4 rb = silu4(b);
    __builtin_nontemporal_store(ra, &out[base]);
    __builtin_nontemporal_store(rb, &out[base + 256]);
}

// Each block: 512 float4 per pass. Grid exact-fit (32768 blocks for 2^26 elems).
__global__ void __launch_bounds__(256)
silu_probe_kernel(const f32x4* __restrict__ in0, f32x4* __restrict__ out0,
                  const f32x4* __restrict__ in1, f32x4* __restrict__ out1,
                  const f32x4* __restrict__ in2, f32x4* __restrict__ out2) {
    long long base = (long long)blockIdx.x * 512 + threadIdx.x;
    silu_pass(in0, out0, base);                 // the real output
    if (in1) silu_pass(in1, out1, base);        // dummy stream 1 (ws)
    if (in2) silu_pass(in2, out2, base);        // dummy stream 2 (ws)
}

__global__ void silu_fwd_tail_kernel(const float* __restrict__ in, float* __restrict__ out,
                                     long long start, long long n) {
    long long i = start + (long long)blockIdx.x * blockDim.x + threadIdx.x;
    if (i < n) out[i] = silu_fast(in[i]);
}

extern "C" void kernel_launch(void* const* d_in, const int* in_sizes, int n_in,
                              void* d_out, int out_size, void* d_ws, size_t ws_size,
                              hipStream_t stream) {
    const float* x = (const float*)d_in[0];
    float* out = (float*)d_out;
    long long n = (long long)in_sizes[0];  // 67,108,864
    size_t sz = (size_t)n * sizeof(float); // 256 MiB

    long long n4 = n / 4;
    long long blocks = n4 / 512;           // 32768

    // Dummy streams carved from d_ws; distinct regions so no L3 reuse.
    const f32x4 *i1 = nullptr, *i2 = nullptr;
    f32x4 *o1 = nullptr, *o2 = nullptr;
    char* ws = (char*)d_ws;
    if (ws_size >= 4 * sz) {
        i1 = (const f32x4*)(ws);          o1 = (f32x4*)(ws + sz);
        i2 = (const f32x4*)(ws + 2 * sz); o2 = (f32x4*)(ws + 3 * sz);
    } else if (ws_size >= 3 * sz) {
        i1 = (const f32x4*)(ws);          o1 = (f32x4*)(ws + sz);
        i2 = (const f32x4*)(ws + 2 * sz); o2 = (f32x4*)(ws);  // timing-only data
    } else if (ws_size >= 2 * sz) {
        i1 = (const f32x4*)(ws);          o1 = (f32x4*)(ws + sz);
    }

    if (blocks > 0) {
        silu_probe_kernel<<<(int)blocks, 256, 0, stream>>>(
            (const f32x4*)x, (f32x4*)out, i1, o1, i2, o2);
    }
    long long done = blocks * 512 * 4;
    long long rem = n - done;
    if (rem > 0) {
        int tgrid = (int)((rem + 255) / 256);
        silu_fwd_tail_kernel<<<tgrid, 256, 0, stream>>>(x, out, done, n);
    }
}